// Round 1
// baseline (277.484 us; speedup 1.0000x reference)
//
#include <hip/hip_runtime.h>

// Project2Dto3D: out[b,c,v] = sum over pixels hw with proj[hw]==v of feat[b,c,hw]
// B=4, C=128, H=240, W=320, V=60*36*60=129600

static constexpr int HW = 240 * 320;      // 76800
static constexpr int V  = 60 * 36 * 60;   // 129600
static constexpr int B  = 4;
static constexpr int C  = 128;
static constexpr int BC = B * C;          // 512

// ---------------------------------------------------------------------------
// Phase 1: head[v] = -1 for all v
__global__ void __launch_bounds__(256) fill_head_kernel(int* __restrict__ head) {
    int i = blockIdx.x * 256 + threadIdx.x;
    if (i < V) head[i] = -1;
}

// Phase 2: per-voxel linked list of pixels via atomicExch
//   next[hw] = old head[v]; head[v] = hw
__global__ void __launch_bounds__(256) build_list_kernel(const int* __restrict__ idx,
                                                         int* __restrict__ head,
                                                         int* __restrict__ next) {
    int hw = blockIdx.x * 256 + threadIdx.x;
    if (hw < HW) {
        int v = idx[hw];
        next[hw] = atomicExch(&head[v], hw);
    }
}

// Phase 3: gather. Thread = (voxel v, group of 4 consecutive bc slices).
// Walk v's pixel list once, accumulate 4 sums, write 4 coalesced outputs.
__global__ void __launch_bounds__(256) gather_kernel(const float* __restrict__ feat,
                                                     const int* __restrict__ head,
                                                     const int* __restrict__ next,
                                                     float* __restrict__ out) {
    int v = blockIdx.x * 256 + threadIdx.x;
    if (v >= V) return;
    int bc0 = blockIdx.y * 4;

    const float* f = feat + (long long)bc0 * HW;
    float s0 = 0.f, s1 = 0.f, s2 = 0.f, s3 = 0.f;

    for (int p = head[v]; p >= 0; p = next[p]) {
        s0 += f[p];
        s1 += f[p + HW];
        s2 += f[p + 2 * HW];
        s3 += f[p + 3 * HW];
    }

    long long o = (long long)bc0 * V + v;
    // Nontemporal: keep the 265MB output stream from thrashing the LLC, which
    // needs to hold the 157MB feature array for the random-order pixel reads.
    __builtin_nontemporal_store(s0, &out[o]);
    __builtin_nontemporal_store(s1, &out[o + (long long)V]);
    __builtin_nontemporal_store(s2, &out[o + 2LL * V]);
    __builtin_nontemporal_store(s3, &out[o + 3LL * V]);
}

extern "C" void kernel_launch(void* const* d_in, const int* in_sizes, int n_in,
                              void* d_out, int out_size, void* d_ws, size_t ws_size,
                              hipStream_t stream) {
    const float* feat = (const float*)d_in[0];   // [4,128,240,320] f32
    const int*   idx  = (const int*)d_in[1];     // [240,320] int
    float*       out  = (float*)d_out;           // [4,128,129600] f32

    // workspace: head[V] ints, next[HW] ints  (~826 KB)
    int* head = (int*)d_ws;
    int* next = head + V;

    fill_head_kernel<<<(V + 255) / 256, 256, 0, stream>>>(head);
    build_list_kernel<<<(HW + 255) / 256, 256, 0, stream>>>(idx, head, next);

    dim3 grid((V + 255) / 256, BC / 4);
    gather_kernel<<<grid, 256, 0, stream>>>(feat, head, next, out);
}